// Round 1
// baseline (120.017 us; speedup 1.0000x reference)
//
#include <hip/hip_runtime.h>

// Radix2ModGroup: per 8-element group, quantize to int8-magnitude (SF=0.05),
// keep the 12 largest-exponent power-of-two terms across the group
// (ties -> lowest element index), reconstruct.

constexpr float SF = 0.05f;
constexpr int GS = 8;          // group size
constexpr int NUM_EXPS = 12;   // term budget per group
constexpr int MAXBITS = 8;     // bits per magnitude
constexpr float QMAXF = 255.0f;

__global__ __launch_bounds__(256) void radix2_mod_group_kernel(
    const float* __restrict__ x, float* __restrict__ out, int ngroups) {
  int g = blockIdx.x * blockDim.x + threadIdx.x;
  if (g >= ngroups) return;

  const float4* __restrict__ xv = reinterpret_cast<const float4*>(x);
  float4 a = xv[2 * g];
  float4 b = xv[2 * g + 1];
  float v[GS] = {a.x, a.y, a.z, a.w, b.x, b.y, b.z, b.w};

  int mag[GS];
  int neg[GS];
#pragma unroll
  for (int i = 0; i < GS; ++i) {
    // jnp.round = round half to even -> rintf (RTNE default mode).
    // Division must stay IEEE (x / 0.05f != x * 20.0f bitwise).
    float r = rintf(v[i] / SF);
    r = fminf(fmaxf(r, -QMAXF), QMAXF);
    int q = (int)r;
    neg[i] = (q < 0);
    mag[i] = neg[i] ? -q : q;
  }

  // Greedy budget selection: highest exponent first; within a level,
  // lowest element index first (matches lax.top_k stable tie-break on
  // flat index i*MAXBITS + e).
  int budget = NUM_EXPS;
  unsigned keepm[GS] = {0, 0, 0, 0, 0, 0, 0, 0};
#pragma unroll
  for (int e = MAXBITS - 1; e >= 0; --e) {
    unsigned m = 0;
#pragma unroll
    for (int i = 0; i < GS; ++i) m |= (((unsigned)mag[i] >> e) & 1u) << i;
    int cnt = __popc(m);
    unsigned kept;
    if (cnt <= budget) {
      kept = m;
      budget -= cnt;
    } else {
      kept = 0u;
      unsigned mm = m;
      for (int k = 0; k < budget; ++k) {  // lowest set bits = lowest indices
        kept |= mm & (0u - mm);
        mm &= mm - 1u;
      }
      budget = 0;
    }
#pragma unroll
    for (int i = 0; i < GS; ++i) keepm[i] |= ((kept >> i) & 1u) << e;
  }

  float o[GS];
#pragma unroll
  for (int i = 0; i < GS; ++i) {
    int r = mag[i] & (int)keepm[i];
    float f = (float)r * SF;
    o[i] = neg[i] ? -f : f;
  }

  float4* __restrict__ ov = reinterpret_cast<float4*>(out);
  ov[2 * g] = make_float4(o[0], o[1], o[2], o[3]);
  ov[2 * g + 1] = make_float4(o[4], o[5], o[6], o[7]);
}

extern "C" void kernel_launch(void* const* d_in, const int* in_sizes, int n_in,
                              void* d_out, int out_size, void* d_ws, size_t ws_size,
                              hipStream_t stream) {
  const float* x = (const float*)d_in[0];
  float* out = (float*)d_out;
  int n = in_sizes[0];
  int ngroups = n / GS;
  int block = 256;
  int grid = (ngroups + block - 1) / block;
  radix2_mod_group_kernel<<<grid, block, 0, stream>>>(x, out, ngroups);
}

// Round 2
// 111.925 us; speedup vs baseline: 1.0723x; 1.0723x over previous
//
#include <hip/hip_runtime.h>

// Radix2ModGroup: per 8-element group, quantize to int magnitude (SF=0.05,
// |q|<=255), keep the 12 largest-exponent power-of-two terms across the
// group's 64 (element,bit) candidates (ties -> lowest element index),
// reconstruct.
//
// Branchless formulation: pack the 8 magnitudes into a uint64, 8x8
// bit-transpose so that bit position 8*e + (7-i) encodes candidate (e,i).
// Bit position is then a strict priority (exponent major, low element index
// minor) -> "keep top-12 terms" == "keep top-12 set bits of the word".
// Select via branchless rank-select (drop the P-12 lowest set bits).

constexpr float SF = 0.05f;
constexpr int NUM_EXPS = 12;

__device__ __forceinline__ unsigned long long transpose8x8(unsigned long long x) {
  // bit(8r+c) <-> bit(8c+r)  (Hacker's Delight 8x8 bit-matrix transpose)
  unsigned long long t;
  t = (x ^ (x >> 7)) & 0x00AA00AA00AA00AAull; x ^= t ^ (t << 7);
  t = (x ^ (x >> 14)) & 0x0000CCCC0000CCCCull; x ^= t ^ (t << 14);
  t = (x ^ (x >> 28)) & 0x00000000F0F0F0F0ull; x ^= t ^ (t << 28);
  return x;
}

__global__ __launch_bounds__(256) void radix2_mod_group_kernel(
    const float4* __restrict__ xv, float4* __restrict__ ov, int ngroups) {
  int g = blockIdx.x * blockDim.x + threadIdx.x;
  if (g >= ngroups) return;

  float4 a = xv[2 * g];
  float4 b = xv[2 * g + 1];
  float v[8] = {a.x, a.y, a.z, a.w, b.x, b.y, b.z, b.w};

  // Quantize and pack magnitudes: byte (7-i) of M = |q_i|.
  unsigned long long M = 0ull;
#pragma unroll
  for (int i = 0; i < 8; ++i) {
    // jnp.round == round-half-to-even -> rintf (RTNE). Division stays IEEE.
    float r = rintf(v[i] / SF);
    r = fminf(fmaxf(r, -255.0f), 255.0f);
    int qi = (int)r;
    unsigned mi = (unsigned)(qi < 0 ? -qi : qi);
    M |= (unsigned long long)mi << (8 * (7 - i));
  }

  // w bit (8e + (7-i)) = bit e of mag_i. Position = selection priority.
  unsigned long long w = transpose8x8(M);

  // Drop the j = max(P-12, 0) lowest-priority set bits.
  int P = __popcll(w);
  int j = P > NUM_EXPS ? P - NUM_EXPS : 0;

  // Branchless rank-select: pos = index of the (j+1)-th set bit from LSB.
  unsigned long long xx = w;
  int pos = 0;
  int c;
  c = __popcll(xx & 0xffffffffull);
  { int t = (j >= c); pos += t << 5; j -= t ? c : 0; xx = t ? (xx >> 32) : xx; }
  c = __popc((unsigned)xx & 0xffffu);
  { int t = (j >= c); pos += t << 4; j -= t ? c : 0; xx = t ? (xx >> 16) : xx; }
  c = __popc((unsigned)xx & 0xffu);
  { int t = (j >= c); pos += t << 3; j -= t ? c : 0; xx = t ? (xx >> 8) : xx; }
  c = __popc((unsigned)xx & 0xfu);
  { int t = (j >= c); pos += t << 2; j -= t ? c : 0; xx = t ? (xx >> 4) : xx; }
  c = __popc((unsigned)xx & 0x3u);
  { int t = (j >= c); pos += t << 1; j -= t ? c : 0; xx = t ? (xx >> 2) : xx; }
  c = (int)((unsigned)xx & 1u);
  { int t = (j >= c); pos += t; }

  unsigned long long keep = w & (~0ull << pos);

  // Transpose back: byte (7-i) of Kt = kept magnitude of element i.
  unsigned long long Kt = transpose8x8(keep);

  float o[8];
#pragma unroll
  for (int i = 0; i < 8; ++i) {
    unsigned mi = (unsigned)(Kt >> (8 * (7 - i))) & 0xffu;
    // sign of q == sign of x whenever mag != 0; mag==0 -> output +/-0 == 0.
    o[i] = copysignf((float)mi * SF, v[i]);
  }

  ov[2 * g] = make_float4(o[0], o[1], o[2], o[3]);
  ov[2 * g + 1] = make_float4(o[4], o[5], o[6], o[7]);
}

extern "C" void kernel_launch(void* const* d_in, const int* in_sizes, int n_in,
                              void* d_out, int out_size, void* d_ws, size_t ws_size,
                              hipStream_t stream) {
  const float* x = (const float*)d_in[0];
  float* out = (float*)d_out;
  int n = in_sizes[0];
  int ngroups = n / 8;
  int block = 256;
  int grid = (ngroups + block - 1) / block;
  radix2_mod_group_kernel<<<grid, block, 0, stream>>>(
      (const float4*)x, (float4*)out, ngroups);
}